// Round 3
// baseline (43327.896 us; speedup 1.0000x reference)
//
#include <hip/hip_runtime.h>
#include <hip/hip_bf16.h>
#include <stdint.h>

#define D 128
#define NUM_HOPS 8

// ---------------- Threefry-2x32 (matches jax._src.prng) ----------------
__host__ __device__ inline void tf2x32(uint32_t k0, uint32_t k1,
                                       uint32_t x0, uint32_t x1,
                                       uint32_t* o0, uint32_t* o1) {
  uint32_t ks2 = k0 ^ k1 ^ 0x1BD11BDAu;
  x0 += k0; x1 += k1;
#define TF_RND(r) { x0 += x1; x1 = (x1 << r) | (x1 >> (32 - r)); x1 ^= x0; }
  TF_RND(13) TF_RND(15) TF_RND(26) TF_RND(6)
  x0 += k1; x1 += ks2 + 1u;
  TF_RND(17) TF_RND(29) TF_RND(16) TF_RND(24)
  x0 += ks2; x1 += k0 + 2u;
  TF_RND(13) TF_RND(15) TF_RND(26) TF_RND(6)
  x0 += k0; x1 += k1 + 3u;
  TF_RND(17) TF_RND(29) TF_RND(16) TF_RND(24)
  x0 += k1; x1 += ks2 + 4u;
  TF_RND(13) TF_RND(15) TF_RND(26) TF_RND(6)
  x0 += ks2; x1 += k0 + 5u;
#undef TF_RND
  *o0 = x0; *o1 = x1;
}

// XLA ErfInv32 (Giles polynomial, w = -log1p(-x*x))
__device__ inline float erfinv_f32(float x) {
  float w = -log1pf(-x * x);
  float p;
  if (w < 5.0f) {
    w = w - 2.5f;
    p = 2.81022636e-08f;
    p = fmaf(p, w, 3.43273939e-07f);
    p = fmaf(p, w, -3.5233877e-06f);
    p = fmaf(p, w, -4.39150654e-06f);
    p = fmaf(p, w, 0.00021858087f);
    p = fmaf(p, w, -0.00125372503f);
    p = fmaf(p, w, -0.00417768164f);
    p = fmaf(p, w, 0.246640727f);
    p = fmaf(p, w, 1.50140941f);
  } else {
    w = sqrtf(w) - 3.0f;
    p = -0.000200214257f;
    p = fmaf(p, w, 0.000100950558f);
    p = fmaf(p, w, 0.00134934322f);
    p = fmaf(p, w, -0.00367342844f);
    p = fmaf(p, w, 0.00573950773f);
    p = fmaf(p, w, -0.0076224613f);
    p = fmaf(p, w, 0.00943887047f);
    p = fmaf(p, w, 1.00167406f);
    p = fmaf(p, w, 2.83297682f);
  }
  return p * x;
}

__device__ inline float noise_from_bits(uint32_t bits) {
  const float lo = -0.99999994f;            // nextafter(-1,0) in f32
  uint32_t fb = (bits >> 9) | 0x3f800000u;
  float f = __uint_as_float(fb) - 1.0f;     // [0,1)
  float u = fmaxf(lo, fmaf(f, 2.0f, lo));   // hi-lo rounds to exactly 2.0f
  return 0.1f * (1.41421354f * erfinv_f32(u));
}

// Partitionable threefry: bits[i] = w0 ^ w1 of tf(key, i>>32, i&0xffffffff)
__global__ __launch_bounds__(256) void noise_kernel(float* __restrict__ out,
                                                    uint32_t fk0, uint32_t fk1,
                                                    long n) {
  long t = (long)blockIdx.x * blockDim.x + threadIdx.x;
  if (t >= n) return;
  uint32_t o0, o1;
  tf2x32(fk0, fk1, 0u, (uint32_t)t, &o0, &o1);
  out[t] = noise_from_bits(o0 ^ o1);
}

// Detect int64 edge_index passed raw: odd int32 slots would be the (all-zero)
// high words. 8 uniform cached loads; P(false positive on int32 ids) ~ 1e-40.
__device__ inline bool edges_are_i64(const int* __restrict__ ei) {
  return (ei[1] | ei[3] | ei[5] | ei[7] | ei[9] | ei[11] | ei[13] | ei[15]) == 0;
}

// Scatter-add: 32 lanes per edge, float4 per lane.
__global__ __launch_bounds__(256) void scatter_kernel(const float* __restrict__ cur,
                                                      float* __restrict__ aggr,
                                                      const int* __restrict__ ei,
                                                      long E) {
  long tid = (long)blockIdx.x * blockDim.x + threadIdx.x;
  long e = tid >> 5;
  if (e >= E) return;
  int lane = (int)(tid & 31);
  bool i64 = edges_are_i64(ei);
  long sidx = i64 ? (2 * e) : e;
  long didx = i64 ? (2 * (E + e)) : (E + e);
  int s = ei[sidx];
  int d = ei[didx];
  float4 v = *(const float4*)(cur + (size_t)s * D + lane * 4);
  float* dp = aggr + (size_t)d * D + lane * 4;
  unsafeAtomicAdd(dp + 0, v.x);
  unsafeAtomicAdd(dp + 1, v.y);
  unsafeAtomicAdd(dp + 2, v.z);
  unsafeAtomicAdd(dp + 3, v.w);
}

// Row L2-normalize; one wave (64 lanes x float2) per row. in==out is OK.
__global__ __launch_bounds__(256) void norm_kernel(const float* __restrict__ in,
                                                   float* __restrict__ out, int N) {
  long t = (long)blockIdx.x * blockDim.x + threadIdx.x;
  int row = (int)(t >> 6);
  int lane = (int)(t & 63);
  if (row >= N) return;
  float2 v = *(const float2*)(in + (size_t)row * D + lane * 2);
  float s = v.x * v.x + v.y * v.y;
  #pragma unroll
  for (int off = 32; off > 0; off >>= 1) s += __shfl_xor(s, off, 64);
  float inv = 1.0f / fmaxf(sqrtf(s), 1e-12f);
  float2 o; o.x = v.x * inv; o.y = v.y * inv;
  *(float2*)(out + (size_t)row * D + lane * 2) = o;
}

extern "C" void kernel_launch(void* const* d_in, const int* in_sizes, int n_in,
                              void* d_out, int out_size, void* d_ws, size_t ws_size,
                              hipStream_t stream) {
  const float* x = (const float*)d_in[0];
  const int* ei = (const int*)d_in[1];
  const long N = in_sizes[0] / D;      // 100000
  const long E = in_sizes[1] / 2;      // 3200000
  float* out = (float*)d_out;
  const long ND = N * D;

  // hop 0: normalize x -> out[0]
  {
    long threads = N * 64;
    norm_kernel<<<(int)((threads + 255) / 256), 256, 0, stream>>>(x, out, (int)N);
  }

  // folded keys: fold_in(key(42), k) = threefry2x32((0,42), (0,k))
  uint32_t fk0[NUM_HOPS], fk1[NUM_HOPS];
  for (int k = 0; k < NUM_HOPS; ++k)
    tf2x32(0u, 42u, 0u, (uint32_t)k, &fk0[k], &fk1[k]);

  for (int k = 0; k < NUM_HOPS; ++k) {
    const float* cur = out + (size_t)k * ND;
    float* nxt = out + (size_t)(k + 1) * ND;
    // 1) nxt = sigma * noise_k   (partitionable threefry stream, w0^w1)
    noise_kernel<<<(int)((ND + 255) / 256), 256, 0, stream>>>(nxt, fk0[k], fk1[k], ND);
    // 2) nxt += scatter_add(cur[src] -> rows dst)
    long sthreads = E * 32;
    scatter_kernel<<<(int)((sthreads + 255) / 256), 256, 0, stream>>>(cur, nxt, ei, E);
    // 3) nxt = l2norm_rows(nxt), in place
    long nthreads = N * 64;
    norm_kernel<<<(int)((nthreads + 255) / 256), 256, 0, stream>>>(nxt, nxt, (int)N);
  }
}

// Round 4
// 2141.633 us; speedup vs baseline: 20.2312x; 20.2312x over previous
//
#include <hip/hip_runtime.h>
#include <hip/hip_bf16.h>
#include <stdint.h>

#define D 128
#define NUM_HOPS 8
#define SCAN_BS 256
#define SCAN2_BS 512

// ---------------- Threefry-2x32 (matches jax._src.prng) ----------------
__host__ __device__ inline void tf2x32(uint32_t k0, uint32_t k1,
                                       uint32_t x0, uint32_t x1,
                                       uint32_t* o0, uint32_t* o1) {
  uint32_t ks2 = k0 ^ k1 ^ 0x1BD11BDAu;
  x0 += k0; x1 += k1;
#define TF_RND(r) { x0 += x1; x1 = (x1 << r) | (x1 >> (32 - r)); x1 ^= x0; }
  TF_RND(13) TF_RND(15) TF_RND(26) TF_RND(6)
  x0 += k1; x1 += ks2 + 1u;
  TF_RND(17) TF_RND(29) TF_RND(16) TF_RND(24)
  x0 += ks2; x1 += k0 + 2u;
  TF_RND(13) TF_RND(15) TF_RND(26) TF_RND(6)
  x0 += k0; x1 += k1 + 3u;
  TF_RND(17) TF_RND(29) TF_RND(16) TF_RND(24)
  x0 += k1; x1 += ks2 + 4u;
  TF_RND(13) TF_RND(15) TF_RND(26) TF_RND(6)
  x0 += ks2; x1 += k0 + 5u;
#undef TF_RND
  *o0 = x0; *o1 = x1;
}

// XLA ErfInv32 (Giles polynomial, w = -log1p(-x*x))
__device__ inline float erfinv_f32(float x) {
  float w = -log1pf(-x * x);
  float p;
  if (w < 5.0f) {
    w = w - 2.5f;
    p = 2.81022636e-08f;
    p = fmaf(p, w, 3.43273939e-07f);
    p = fmaf(p, w, -3.5233877e-06f);
    p = fmaf(p, w, -4.39150654e-06f);
    p = fmaf(p, w, 0.00021858087f);
    p = fmaf(p, w, -0.00125372503f);
    p = fmaf(p, w, -0.00417768164f);
    p = fmaf(p, w, 0.246640727f);
    p = fmaf(p, w, 1.50140941f);
  } else {
    w = sqrtf(w) - 3.0f;
    p = -0.000200214257f;
    p = fmaf(p, w, 0.000100950558f);
    p = fmaf(p, w, 0.00134934322f);
    p = fmaf(p, w, -0.00367342844f);
    p = fmaf(p, w, 0.00573950773f);
    p = fmaf(p, w, -0.0076224613f);
    p = fmaf(p, w, 0.00943887047f);
    p = fmaf(p, w, 1.00167406f);
    p = fmaf(p, w, 2.83297682f);
  }
  return p * x;
}

__device__ inline float noise_from_bits(uint32_t bits) {
  const float lo = -0.99999994f;            // nextafter(-1,0) in f32
  uint32_t fb = (bits >> 9) | 0x3f800000u;
  float f = __uint_as_float(fb) - 1.0f;     // [0,1)
  float u = fmaxf(lo, fmaf(f, 2.0f, lo));   // hi-lo rounds to exactly 2.0f
  return 0.1f * (1.41421354f * erfinv_f32(u));
}

// Partitionable threefry element t: bits = w0 ^ w1 of tf(key, t>>32, t&0xffffffff)
__device__ inline float noise_elem(uint32_t fk0, uint32_t fk1, long t) {
  uint32_t o0, o1;
  tf2x32(fk0, fk1, (uint32_t)(((unsigned long)t) >> 32), (uint32_t)t, &o0, &o1);
  return noise_from_bits(o0 ^ o1);
}

// Detect int64 edge_index passed raw (odd int32 slots all-zero high words).
__device__ inline bool edges_are_i64(const int* __restrict__ ei) {
  return (ei[1] | ei[3] | ei[5] | ei[7] | ei[9] | ei[11] | ei[13] | ei[15]) == 0;
}

// ---------------- CSR build ----------------
__global__ __launch_bounds__(256) void hist_kernel(const int* __restrict__ ei,
                                                   int* __restrict__ counts, long E) {
  long e = (long)blockIdx.x * blockDim.x + threadIdx.x;
  if (e >= E) return;
  bool i64 = edges_are_i64(ei);
  int d = ei[i64 ? (2 * (E + e)) : (E + e)];
  atomicAdd(&counts[d], 1);
}

// exclusive scan within 256-chunk; chunk totals to partials
__global__ __launch_bounds__(SCAN_BS) void scan1_kernel(const int* __restrict__ counts,
                                                        int* __restrict__ excl,
                                                        int* __restrict__ partials, int N) {
  __shared__ int lds[SCAN_BS];
  int tid = threadIdx.x;
  int i = blockIdx.x * SCAN_BS + tid;
  int v = (i < N) ? counts[i] : 0;
  lds[tid] = v;
  __syncthreads();
  for (int off = 1; off < SCAN_BS; off <<= 1) {
    int t = (tid >= off) ? lds[tid - off] : 0;
    __syncthreads();
    if (tid >= off) lds[tid] += t;
    __syncthreads();
  }
  int incl = lds[tid];
  if (i < N) excl[i] = incl - v;
  if (tid == SCAN_BS - 1) partials[blockIdx.x] = incl;
}

// exclusive scan of partials (nchunks <= SCAN2_BS), in place
__global__ __launch_bounds__(SCAN2_BS) void scan2_kernel(int* __restrict__ partials, int nchunks) {
  __shared__ int lds[SCAN2_BS];
  int tid = threadIdx.x;
  int v = (tid < nchunks) ? partials[tid] : 0;
  lds[tid] = v;
  __syncthreads();
  for (int off = 1; off < SCAN2_BS; off <<= 1) {
    int t = (tid >= off) ? lds[tid - off] : 0;
    __syncthreads();
    if (tid >= off) lds[tid] += t;
    __syncthreads();
  }
  if (tid < nchunks) partials[tid] = lds[tid] - v;  // exclusive
}

// row_ptr[i] = excl[i] + partials[i/256]; cursor[i] = row_ptr[i]; row_ptr[N] = E
__global__ __launch_bounds__(256) void scan3_kernel(int* __restrict__ row_ptr,
                                                    const int* __restrict__ partials,
                                                    int* __restrict__ cursor, int N, int E) {
  int i = blockIdx.x * blockDim.x + threadIdx.x;
  if (i > N) return;
  if (i == N) { row_ptr[N] = E; return; }
  int v = row_ptr[i] + partials[i >> 8];
  row_ptr[i] = v;
  cursor[i] = v;
}

__global__ __launch_bounds__(256) void fill_kernel(const int* __restrict__ ei,
                                                   int* __restrict__ cursor,
                                                   int* __restrict__ col, long E) {
  long e = (long)blockIdx.x * blockDim.x + threadIdx.x;
  if (e >= E) return;
  bool i64 = edges_are_i64(ei);
  int s = ei[i64 ? (2 * e) : e];
  int d = ei[i64 ? (2 * (E + e)) : (E + e)];
  int slot = atomicAdd(&cursor[d], 1);
  col[slot] = s;
}

// ---------------- Fused per-hop: noise + CSR gather + L2 normalize ----------------
// One wave (64 lanes x float2) per destination row.
__global__ __launch_bounds__(256) void gather_hop(const float* __restrict__ cur,
                                                  float* __restrict__ nxt,
                                                  const int* __restrict__ row_ptr,
                                                  const int* __restrict__ col,
                                                  int N, uint32_t fk0, uint32_t fk1) {
  long t = (long)blockIdx.x * blockDim.x + threadIdx.x;
  int row = (int)(t >> 6);
  int lane = (int)(t & 63);
  if (row >= N) return;

  long t0 = (long)row * D + lane * 2;
  float2 acc;
  acc.x = noise_elem(fk0, fk1, t0);
  acc.y = noise_elem(fk0, fk1, t0 + 1);

  int beg = row_ptr[row], end = row_ptr[row + 1];
  int i = beg;
  for (; i + 4 <= end; i += 4) {
    int s0 = col[i], s1 = col[i + 1], s2 = col[i + 2], s3 = col[i + 3];
    float2 v0 = *(const float2*)(cur + (size_t)s0 * D + lane * 2);
    float2 v1 = *(const float2*)(cur + (size_t)s1 * D + lane * 2);
    float2 v2 = *(const float2*)(cur + (size_t)s2 * D + lane * 2);
    float2 v3 = *(const float2*)(cur + (size_t)s3 * D + lane * 2);
    acc.x += v0.x + v1.x + v2.x + v3.x;
    acc.y += v0.y + v1.y + v2.y + v3.y;
  }
  for (; i < end; ++i) {
    int s = col[i];
    float2 v = *(const float2*)(cur + (size_t)s * D + lane * 2);
    acc.x += v.x; acc.y += v.y;
  }

  float ss = acc.x * acc.x + acc.y * acc.y;
  #pragma unroll
  for (int off = 32; off > 0; off >>= 1) ss += __shfl_xor(ss, off, 64);
  float inv = 1.0f / fmaxf(sqrtf(ss), 1e-12f);
  float2 o; o.x = acc.x * inv; o.y = acc.y * inv;
  *(float2*)(nxt + (size_t)row * D + lane * 2) = o;
}

// ---------------- Fallback path kernels (round-3, atomic scatter) ----------------
__global__ __launch_bounds__(256) void noise_kernel(float* __restrict__ out,
                                                    uint32_t fk0, uint32_t fk1, long n) {
  long t = (long)blockIdx.x * blockDim.x + threadIdx.x;
  if (t >= n) return;
  out[t] = noise_elem(fk0, fk1, t);
}

__global__ __launch_bounds__(256) void scatter_kernel(const float* __restrict__ cur,
                                                      float* __restrict__ aggr,
                                                      const int* __restrict__ ei, long E) {
  long tid = (long)blockIdx.x * blockDim.x + threadIdx.x;
  long e = tid >> 5;
  if (e >= E) return;
  int lane = (int)(tid & 31);
  bool i64 = edges_are_i64(ei);
  int s = ei[i64 ? (2 * e) : e];
  int d = ei[i64 ? (2 * (E + e)) : (E + e)];
  float4 v = *(const float4*)(cur + (size_t)s * D + lane * 4);
  float* dp = aggr + (size_t)d * D + lane * 4;
  unsafeAtomicAdd(dp + 0, v.x);
  unsafeAtomicAdd(dp + 1, v.y);
  unsafeAtomicAdd(dp + 2, v.z);
  unsafeAtomicAdd(dp + 3, v.w);
}

// Row L2-normalize; one wave per row. in==out OK.
__global__ __launch_bounds__(256) void norm_kernel(const float* __restrict__ in,
                                                   float* __restrict__ out, int N) {
  long t = (long)blockIdx.x * blockDim.x + threadIdx.x;
  int row = (int)(t >> 6);
  int lane = (int)(t & 63);
  if (row >= N) return;
  float2 v = *(const float2*)(in + (size_t)row * D + lane * 2);
  float s = v.x * v.x + v.y * v.y;
  #pragma unroll
  for (int off = 32; off > 0; off >>= 1) s += __shfl_xor(s, off, 64);
  float inv = 1.0f / fmaxf(sqrtf(s), 1e-12f);
  float2 o; o.x = v.x * inv; o.y = v.y * inv;
  *(float2*)(out + (size_t)row * D + lane * 2) = o;
}

extern "C" void kernel_launch(void* const* d_in, const int* in_sizes, int n_in,
                              void* d_out, int out_size, void* d_ws, size_t ws_size,
                              hipStream_t stream) {
  const float* x = (const float*)d_in[0];
  const int* ei = (const int*)d_in[1];
  const long N = in_sizes[0] / D;      // 100000
  const long E = in_sizes[1] / 2;      // 3200000
  float* out = (float*)d_out;
  const long ND = N * D;

  // folded keys: fold_in(key(42), k) = threefry2x32((0,42), (0,k))
  uint32_t fk0[NUM_HOPS], fk1[NUM_HOPS];
  for (int k = 0; k < NUM_HOPS; ++k)
    tf2x32(0u, 42u, 0u, (uint32_t)k, &fk0[k], &fk1[k]);

  // hop 0: normalize x -> out[0]
  {
    long threads = N * 64;
    norm_kernel<<<(int)((threads + 255) / 256), 256, 0, stream>>>(x, out, (int)N);
  }

  // Workspace layout (ints): row_ptr[N+1] | counts[N] (reused as cursor) | partials[nchunks] | col[E]
  const int nchunks = (int)((N + SCAN_BS - 1) / SCAN_BS);
  size_t need = ((size_t)(N + 1) + (size_t)N + (size_t)nchunks + (size_t)E) * sizeof(int);

  if (ws_size >= need && nchunks <= SCAN2_BS) {
    int* row_ptr  = (int*)d_ws;
    int* counts   = row_ptr + (N + 1);     // later reused as cursor
    int* partials = counts + N;
    int* col      = partials + nchunks;

    hipMemsetAsync(counts, 0, (size_t)N * sizeof(int), stream);
    hist_kernel<<<(int)((E + 255) / 256), 256, 0, stream>>>(ei, counts, E);
    scan1_kernel<<<nchunks, SCAN_BS, 0, stream>>>(counts, row_ptr, partials, (int)N);
    scan2_kernel<<<1, SCAN2_BS, 0, stream>>>(partials, nchunks);
    scan3_kernel<<<(int)((N + 256) / 256), 256, 0, stream>>>(row_ptr, partials, counts, (int)N, (int)E);
    fill_kernel<<<(int)((E + 255) / 256), 256, 0, stream>>>(ei, counts, col, E);

    long nthreads = N * 64;
    int ngrid = (int)((nthreads + 255) / 256);
    for (int k = 0; k < NUM_HOPS; ++k) {
      const float* cur = out + (size_t)k * ND;
      float* nxt = out + (size_t)(k + 1) * ND;
      gather_hop<<<ngrid, 256, 0, stream>>>(cur, nxt, row_ptr, col, (int)N, fk0[k], fk1[k]);
    }
  } else {
    // Fallback: proven round-3 atomic path
    for (int k = 0; k < NUM_HOPS; ++k) {
      const float* cur = out + (size_t)k * ND;
      float* nxt = out + (size_t)(k + 1) * ND;
      noise_kernel<<<(int)((ND + 255) / 256), 256, 0, stream>>>(nxt, fk0[k], fk1[k], ND);
      long sthreads = E * 32;
      scatter_kernel<<<(int)((sthreads + 255) / 256), 256, 0, stream>>>(cur, nxt, ei, E);
      long nthreads = N * 64;
      norm_kernel<<<(int)((nthreads + 255) / 256), 256, 0, stream>>>(nxt, nxt, (int)N);
    }
  }
}